// Round 4
// baseline (950.074 us; speedup 1.0000x reference)
//
#include <hip/hip_runtime.h>
#include <hip/hip_bf16.h>
#include <math.h>

// Problem constants (fixed by the reference)
#define DD    768
#define NNN   100000
#define NC_   64
#define BB_   8192
#define CC_   10
#define KTOP  50
#define NN4_  25000      // NNN/4
#define NBIN  4096
#define MAXC  2048

// ---- workspace layout (float offsets) ----
#define WS_S    0          // S [64][100000]
#define WS_TN   6400000    // t_norm2 [100000]
#define WS_CN   6500000    // c_norm2 [64]
#define WS_GRAM 6500064    // gram [64*64]
#define WS_P    6504160    // P = C^T W^T [64*10]
#define WS_X    6504800    // X = G^-1 P [64*10]
#define WS_U    6505440    // U = E C [8192*64]
#define WS_MNB  7029728    // int[64] per-concept d2 min bits
#define WS_MXB  7029792    // int[64] per-concept d2 max bits
// total ~28.2 MB

// ============ K_A: gram, c_norm2, P, init min/max ============
__global__ __launch_bounds__(256) void k_gram(
    const float* __restrict__ C, const float* __restrict__ W,
    float* __restrict__ gram, float* __restrict__ cn2, float* __restrict__ P,
    int* __restrict__ mnb, int* __restrict__ mxb)
{
  __shared__ float red[256];
  int c = blockIdx.x, t = threadIdx.x;
  int j = t & 63, part = t >> 6;
  float acc = 0.f;
  for (int d = part; d < DD; d += 4)
    acc = fmaf(C[d*NC_ + c], C[d*NC_ + j], acc);
  red[t] = acc;
  __syncthreads();
  if (part == 0) {
    float v = red[j] + red[j+64] + red[j+128] + red[j+192];
    gram[c*NC_ + j] = v;
    if (j == c) cn2[c] = v;
  }
  if (t == 0) { mnb[c] = 0x7f7fffff; mxb[c] = 0; }
  for (int jj = 0; jj < CC_; jj++) {
    float a = 0.f;
    for (int d = t; d < DD; d += 256)
      a = fmaf(C[d*NC_ + c], W[jj*DD + d], a);
    __syncthreads();
    red[t] = a;
    __syncthreads();
    for (int off = 128; off > 0; off >>= 1) {
      if (t < off) red[t] += red[t+off];
      __syncthreads();
    }
    if (t == 0) P[c*CC_ + jj] = red[0];
  }
}

// ============ K_B: Gauss-Jordan solve G X = P, gram scalars ============
__global__ __launch_bounds__(256) void k_solve(
    const float* __restrict__ gram, const float* __restrict__ P,
    float* __restrict__ X, float* __restrict__ outsc)
{
  __shared__ float A[NC_][76];   // [G | P], 74 used cols
  __shared__ float mcol[NC_];
  __shared__ float r1[256], r2[256], r3[256];
  int t = threadIdx.x;
  for (int i = t; i < NC_*NC_; i += 256) A[i >> 6][i & 63] = gram[i];
  for (int i = t; i < NC_*CC_; i += 256) A[i / CC_][64 + i % CC_] = P[i];
  float s_all = 0.f, s_diag = 0.f, s_dev = 0.f;
  for (int i = t; i < NC_*NC_; i += 256) {
    float g = gram[i];
    int rr = i >> 6, cc = i & 63;
    s_all += g;
    if (rr == cc) { s_diag += g; s_dev += fabsf(g - 1.f); }
    else s_dev += fabsf(g);
  }
  r1[t] = s_all; r2[t] = s_diag; r3[t] = s_dev;
  __syncthreads();
  for (int off = 128; off > 0; off >>= 1) {
    if (t < off) { r1[t] += r1[t+off]; r2[t] += r2[t+off]; r3[t] += r3[t+off]; }
    __syncthreads();
  }
  if (t == 0) {
    outsc[0] = 0.f;                            // L_sparse_1 accumulator (k_topk adds)
    outsc[1] = (r1[0] - r2[0]) * (1.f/4096.f); // L_sparse_2
    outsc[2] = r2[0] * (1.f/4096.f);           // norm_metrics
    outsc[3] = r3[0] * (1.f/4096.f);           // similarity_penalty
  }
  for (int i = 0; i < NC_; i++) {
    __syncthreads();
    float piv = A[i][i];
    __syncthreads();
    if (t < 74) A[i][t] = A[i][t] / piv;
    __syncthreads();
    if (t < NC_) mcol[t] = A[t][i];
    __syncthreads();
    for (int e = t; e < NC_*74; e += 256) {
      int rr = e / 74, jj = e - rr*74;
      if (rr != i) A[rr][jj] = fmaf(-mcol[rr], A[i][jj], A[rr][jj]);
    }
  }
  __syncthreads();
  for (int i = t; i < NC_*CC_; i += 256) X[i] = A[i / CC_][64 + i % CC_];
}

// ============ K_C: fused U = E@C and orig_pred = E@W^T + b ============
// Block: 32 E-rows x 96 cols (0..63 -> U, 64..73 -> orig_pred, rest pad).
__global__ __launch_bounds__(192) void k_EU(
    const float* __restrict__ E, const float* __restrict__ C,
    const float* __restrict__ W, const float* __restrict__ bias,
    float* __restrict__ U, float* __restrict__ orig)
{
  __shared__ __align__(16) float Et[32][36];  // [kk][row]
  __shared__ __align__(16) float Vt[32][96];  // [kk][col]
  int t = threadIdx.x;
  int r0 = blockIdx.x * 32;
  int rg = t & 15;       // rows rg*2, rg*2+1
  int cg = t >> 4;       // 0..11 -> cols cg*8..+7
  float acc[2][8] = {};
  for (int k0 = 0; k0 < DD; k0 += 32) {
    for (int lin = t; lin < 256; lin += 192) {        // 32 rows x 8 float4
      int row = lin >> 3, kq = (lin & 7) * 4;
      float4 v = *(const float4*)&E[(size_t)(r0+row)*DD + k0 + kq];
      Et[kq+0][row] = v.x; Et[kq+1][row] = v.y; Et[kq+2][row] = v.z; Et[kq+3][row] = v.w;
    }
    for (int lin = t; lin < 32*96; lin += 192) {
      int kk = lin / 96, cc = lin - kk*96;
      float v = 0.f;
      if (cc < 64)      v = C[(k0+kk)*NC_ + cc];
      else if (cc < 74) v = W[(cc-64)*DD + k0 + kk];
      Vt[kk][cc] = v;
    }
    __syncthreads();
    #pragma unroll 8
    for (int kk = 0; kk < 32; kk++) {
      float2 e2 = *(const float2*)&Et[kk][rg*2];
      float4 b0 = *(const float4*)&Vt[kk][cg*8];
      float4 b1 = *(const float4*)&Vt[kk][cg*8+4];
      float ev[2] = {e2.x, e2.y};
      float bv[8] = {b0.x,b0.y,b0.z,b0.w,b1.x,b1.y,b1.z,b1.w};
      #pragma unroll
      for (int r = 0; r < 2; r++)
        #pragma unroll
        for (int q = 0; q < 8; q++)
          acc[r][q] = fmaf(ev[r], bv[q], acc[r][q]);
    }
    __syncthreads();
  }
  #pragma unroll
  for (int r = 0; r < 2; r++) {
    int row = r0 + rg*2 + r;
    #pragma unroll
    for (int q = 0; q < 8; q++) {
      int col = cg*8 + q;
      if (col < NC_)      U[(size_t)row*NC_ + col] = acc[r][q];
      else if (col < 74)  orig[row*CC_ + (col-64)] = acc[r][q] + bias[col-64];
    }
  }
}

// ============ K_D: y_pred = U @ X + b ============
__global__ __launch_bounds__(256) void k_ypred(
    const float* __restrict__ U, const float* __restrict__ X,
    const float* __restrict__ bias, float* __restrict__ yp)
{
  __shared__ float Xs[NC_*CC_];
  __shared__ float bs[CC_];
  int t = threadIdx.x;
  for (int i = t; i < NC_*CC_; i += 256) Xs[i] = X[i];
  if (t < CC_) bs[t] = bias[t];
  __syncthreads();
  int r = blockIdx.x * 256 + t;
  float acc[CC_];
  #pragma unroll
  for (int j = 0; j < CC_; j++) acc[j] = bs[j];
  const float4* Ur = (const float4*)(U + (size_t)r * NC_);
  #pragma unroll 4
  for (int k4 = 0; k4 < 16; k4++) {
    float4 u = Ur[k4];
    float uv[4] = {u.x,u.y,u.z,u.w};
    #pragma unroll
    for (int kq = 0; kq < 4; kq++)
      #pragma unroll
      for (int j = 0; j < CC_; j++)
        acc[j] = fmaf(uv[kq], Xs[(k4*4+kq)*CC_ + j], acc[j]);
  }
  #pragma unroll
  for (int j = 0; j < CC_; j++) yp[(size_t)r*CC_ + j] = acc[j];
}

// ============ K_E: S = C^T T  (+ fused t_norm2, per-concept d2 min/max) ============
// Block: 64 concepts x 256 cols. 256 threads, 8x8 per thread.
__global__ __launch_bounds__(256) void k_bigS(
    const float* __restrict__ C, const float* __restrict__ T,
    float* __restrict__ S, float* __restrict__ tn2, const float* __restrict__ cn2,
    int* __restrict__ mnb, int* __restrict__ mxb)
{
  __shared__ __align__(16) float Ct[32][64];
  __shared__ __align__(16) float Tt[32][256];
  __shared__ int smn[64], smx[64];
  int t = threadIdx.x;
  int j0 = blockIdx.x * 256;
  int colg = t & 31, cgrp = t >> 5;
  int mycol = (t & 63) * 4;   // staging column group (constant per thread)
  int myrow = t >> 6;         // staging row phase 0..3
  float acc[8][8] = {};
  float4 tn4 = {0.f,0.f,0.f,0.f};
  for (int k0 = 0; k0 < DD; k0 += 32) {
    #pragma unroll
    for (int p = 0; p < 2; p++) {           // stage C chunk [32][64]
      int lin = t + p*256;
      int row = lin >> 4, c4 = (lin & 15) * 4;
      *(float4*)&Ct[row][c4] = *(const float4*)&C[(k0+row)*NC_ + c4];
    }
    #pragma unroll
    for (int p = 0; p < 8; p++) {           // stage T chunk [32][256] + norms
      int row = myrow + p*4;
      float4 v = {0.f,0.f,0.f,0.f};
      if (j0 + mycol < NNN)
        v = *(const float4*)&T[(size_t)(k0+row)*NNN + j0 + mycol];
      *(float4*)&Tt[row][mycol] = v;
      tn4.x = fmaf(v.x,v.x,tn4.x); tn4.y = fmaf(v.y,v.y,tn4.y);
      tn4.z = fmaf(v.z,v.z,tn4.z); tn4.w = fmaf(v.w,v.w,tn4.w);
    }
    __syncthreads();
    #pragma unroll 8
    for (int kk = 0; kk < 32; kk++) {
      float4 a0 = *(const float4*)&Ct[kk][cgrp*4];
      float4 a1 = *(const float4*)&Ct[kk][32 + cgrp*4];
      float4 b0 = *(const float4*)&Tt[kk][colg*4];
      float4 b1 = *(const float4*)&Tt[kk][128 + colg*4];
      float av[8] = {a0.x,a0.y,a0.z,a0.w,a1.x,a1.y,a1.z,a1.w};
      float bv[8] = {b0.x,b0.y,b0.z,b0.w,b1.x,b1.y,b1.z,b1.w};
      #pragma unroll
      for (int i = 0; i < 8; i++)
        #pragma unroll
        for (int jq = 0; jq < 8; jq++)
          acc[i][jq] = fmaf(av[i], bv[jq], acc[i][jq]);
    }
    __syncthreads();
  }
  // reduce t_norm2 partials (4 row-phases per column) via Tt rows 0..4
  *(float4*)&Tt[myrow][mycol] = tn4;
  __syncthreads();
  if (t < 64) {
    float4 s0 = *(const float4*)&Tt[0][t*4];
    float4 s1 = *(const float4*)&Tt[1][t*4];
    float4 s2 = *(const float4*)&Tt[2][t*4];
    float4 s3 = *(const float4*)&Tt[3][t*4];
    float4 ft;
    ft.x = (s0.x+s1.x)+(s2.x+s3.x); ft.y = (s0.y+s1.y)+(s2.y+s3.y);
    ft.z = (s0.z+s1.z)+(s2.z+s3.z); ft.w = (s0.w+s1.w)+(s2.w+s3.w);
    *(float4*)&Tt[4][t*4] = ft;
    if (j0 + t*4 < NNN) *(float4*)&tn2[j0 + t*4] = ft;
    smn[t] = 0x7f7fffff; smx[t] = 0;
  }
  __syncthreads();
  float4 tA = *(const float4*)&Tt[4][colg*4];
  float4 tB = *(const float4*)&Tt[4][128 + colg*4];
  float tnv[8] = {tA.x,tA.y,tA.z,tA.w,tB.x,tB.y,tB.z,tB.w};
  bool valA = (j0 + colg*4) < NNN;
  bool valB = (j0 + 128 + colg*4) < NNN;
  #pragma unroll
  for (int i = 0; i < 8; i++) {
    int c = (i < 4) ? (cgrp*4 + i) : (32 + cgrp*4 + (i-4));
    float cn = cn2[c];
    size_t base = (size_t)c * NNN + j0;
    if (valA) { float4 w = {acc[i][0],acc[i][1],acc[i][2],acc[i][3]}; *(float4*)&S[base + colg*4] = w; }
    if (valB) { float4 w = {acc[i][4],acc[i][5],acc[i][6],acc[i][7]}; *(float4*)&S[base + 128 + colg*4] = w; }
    float lmn = 1e30f, lmx = -1e30f;
    #pragma unroll
    for (int q = 0; q < 8; q++) {
      bool ok = (q < 4) ? valA : valB;
      if (ok) {
        float d2 = fmaf(-2.f, acc[i][q], cn + tnv[q]);
        lmn = fminf(lmn, d2); lmx = fmaxf(lmx, d2);
      }
    }
    if (lmn <= lmx) {
      atomicMin(&smn[c], __float_as_int(lmn));   // d2 > 0 -> int-bit compare valid
      atomicMax(&smx[c], __float_as_int(lmx));
    }
  }
  __syncthreads();
  if (t < 64) {
    atomicMin(&mnb[t], smn[t]);
    atomicMax(&mxb[t], smx[t]);
  }
}

// ============ K_F: per-concept top-50 smallest d2, accumulate L_sparse_1 ============
__device__ __forceinline__ int d2bin(float d2, float mn, float scale) {
  int b = (int)((d2 - mn) * scale);
  b = b < 0 ? 0 : b;
  return b > (NBIN-1) ? (NBIN-1) : b;
}

__global__ __launch_bounds__(1024) void k_topk(
    const float* __restrict__ S, const float* __restrict__ tn2,
    const float* __restrict__ cn2, const int* __restrict__ mnb,
    const int* __restrict__ mxb, float* __restrict__ Lout)
{
  __shared__ unsigned int hist[NBIN];
  __shared__ unsigned int tth[1024];
  __shared__ unsigned int gth[32];
  __shared__ float cd2[MAXC];
  __shared__ float cs_[MAXC];
  __shared__ int   ci_[MAXC];
  __shared__ int ncand;
  __shared__ int bstar_s;
  __shared__ unsigned int cntb_s;
  __shared__ float redf[1024];
  int c = blockIdx.x, t = threadIdx.x;
  float cn = cn2[c];
  float mn = __int_as_float(mnb[c]);
  float mx = __int_as_float(mxb[c]);
  float scale = (float)NBIN / fmaxf(mx - mn, 1e-12f);
  for (int i = t; i < NBIN; i += 1024) hist[i] = 0u;
  if (t == 0) ncand = 0;
  __syncthreads();
  const float4* Sr = (const float4*)(S + (size_t)c * NNN);
  const float4* Tn = (const float4*)tn2;
  for (int i = t; i < NN4_; i += 1024) {
    float4 s4 = Sr[i];
    float4 t4 = Tn[i];
    atomicAdd(&hist[d2bin(fmaf(-2.f, s4.x, cn + t4.x), mn, scale)], 1u);
    atomicAdd(&hist[d2bin(fmaf(-2.f, s4.y, cn + t4.y), mn, scale)], 1u);
    atomicAdd(&hist[d2bin(fmaf(-2.f, s4.z, cn + t4.z), mn, scale)], 1u);
    atomicAdd(&hist[d2bin(fmaf(-2.f, s4.w, cn + t4.w), mn, scale)], 1u);
  }
  __syncthreads();
  // inclusive cumsum of hist (4 bins per thread + 2-level scan)
  int base = t * 4;
  unsigned h0 = hist[base], h1 = hist[base+1], h2 = hist[base+2], h3 = hist[base+3];
  unsigned i0 = h0, i1 = i0 + h1, i2 = i1 + h2, i3 = i2 + h3;
  tth[t] = i3;
  __syncthreads();
  if (t < 32) { unsigned s = 0; for (int q = 0; q < 32; q++) s += tth[t*32+q]; gth[t] = s; }
  __syncthreads();
  if (t == 0) { unsigned s = 0; for (int q = 0; q < 32; q++) { unsigned x = gth[q]; gth[q] = s; s += x; } }
  __syncthreads();
  if (t < 32) { unsigned s = gth[t]; for (int q = 0; q < 32; q++) { unsigned x = tth[t*32+q]; tth[t*32+q] = s; s += x; } }
  __syncthreads();
  unsigned off = tth[t];     // exclusive prefix for this thread's 4 bins
  hist[base]   = off + i0;
  hist[base+1] = off + i1;
  hist[base+2] = off + i2;
  hist[base+3] = off + i3;
  __syncthreads();
  #pragma unroll
  for (int q = 0; q < 4; q++) {
    int bb = base + q;
    unsigned cum = hist[bb];
    unsigned prev = (bb == 0) ? 0u : hist[bb-1];
    if (cum >= (unsigned)KTOP && prev < (unsigned)KTOP) { bstar_s = bb; cntb_s = prev; }
  }
  __syncthreads();
  int bstar = bstar_s;
  unsigned cntb = cntb_s;
  float ssum = 0.f;
  for (int i = t; i < NN4_; i += 1024) {
    float4 s4 = Sr[i];
    float4 t4 = Tn[i];
    float sv[4] = {s4.x, s4.y, s4.z, s4.w};
    float tv[4] = {t4.x, t4.y, t4.z, t4.w};
    #pragma unroll
    for (int q = 0; q < 4; q++) {
      float dd = fmaf(-2.f, sv[q], cn + tv[q]);
      int b = d2bin(dd, mn, scale);
      if (b < bstar) ssum += sv[q];
      else if (b == bstar) {
        int id = atomicAdd(&ncand, 1);
        if (id < MAXC) { cd2[id] = dd; cs_[id] = sv[q]; ci_[id] = i*4 + q; }
      }
    }
  }
  redf[t] = ssum;
  __syncthreads();
  for (int offr = 512; offr > 0; offr >>= 1) {
    if (t < offr) redf[t] += redf[t + offr];
    __syncthreads();
  }
  if (t == 0) {
    int nc = ncand < MAXC ? ncand : MAXC;
    int need = KTOP - (int)cntb;
    float extra = 0.f;
    for (int sel = 0; sel < need; sel++) {        // stable (d2, idx) selection
      float bd = 3.4e38f; int bi = -1; int bx = 0x7fffffff;
      for (int q = 0; q < nc; q++) {
        if (ci_[q] >= 0) {
          float dq = cd2[q];
          if (dq < bd || (dq == bd && ci_[q] < bx)) { bd = dq; bi = q; bx = ci_[q]; }
        }
      }
      if (bi < 0) break;
      extra += cs_[bi];
      ci_[bi] = -1;
    }
    atomicAdd(Lout, (redf[0] + extra) * (1.f / (float)(KTOP * NC_)));
  }
}

// ============ host-side launch ============
extern "C" void kernel_launch(void* const* d_in, const int* in_sizes, int n_in,
                              void* d_out, int out_size, void* d_ws, size_t ws_size,
                              hipStream_t stream) {
  const float* E    = (const float*)d_in[0];  // train_embedding [8192,768]
  const float* Cm   = (const float*)d_in[2];  // concept [768,64]
  const float* Tm   = (const float*)d_in[3];  // train_embeddings_T [768,100000]
  const float* W    = (const float*)d_in[4];  // [10,768]
  const float* bias = (const float*)d_in[5];  // [10]
  float* out = (float*)d_out;
  float* ws  = (float*)d_ws;

  float* S    = ws + WS_S;
  float* tn2  = ws + WS_TN;
  float* cn2  = ws + WS_CN;
  float* gram = ws + WS_GRAM;
  float* P    = ws + WS_P;
  float* X    = ws + WS_X;
  float* U    = ws + WS_U;
  int*   mnb  = (int*)(ws + WS_MNB);
  int*   mxb  = (int*)(ws + WS_MXB);

  float* orig = out;            // [0 .. 81919]
  float* yp   = out + 81920;    // [81920 .. 163839]
  float* sc   = out + 163840;   // L_sparse_1, L_sparse_2, norm_metrics, similarity_penalty

  hipLaunchKernelGGL(k_gram,  dim3(64),  dim3(256),  0, stream, Cm, W, gram, cn2, P, mnb, mxb);
  hipLaunchKernelGGL(k_solve, dim3(1),   dim3(256),  0, stream, gram, P, X, sc);
  hipLaunchKernelGGL(k_EU,    dim3(256), dim3(192),  0, stream, E, Cm, W, bias, U, orig);
  hipLaunchKernelGGL(k_ypred, dim3(32),  dim3(256),  0, stream, U, X, bias, yp);
  hipLaunchKernelGGL(k_bigS,  dim3(391), dim3(256),  0, stream, Cm, Tm, S, tn2, cn2, mnb, mxb);
  hipLaunchKernelGGL(k_topk,  dim3(64),  dim3(1024), 0, stream, S, tn2, cn2, mnb, mxb, sc);
}

// Round 7
// 875.983 us; speedup vs baseline: 1.0846x; 1.0846x over previous
//
#include <hip/hip_runtime.h>
#include <hip/hip_bf16.h>
#include <math.h>

// Problem constants (fixed by the reference)
#define DD    768
#define NNN   100000
#define NC_   64
#define BB_   8192
#define CC_   10
#define KTOP  50
#define NN4_  25000      // NNN/4
#define NBIN  4096
#define SLICE_N4 6250    // (NNN/4)/4 float4s per slice
#define CCAP  1024       // candidate cap per concept

// ---- workspace layout (float offsets) ----
#define WS_S    0          // S [64][100000]
#define WS_TN   6400000    // t_norm2 [100000]
#define WS_CN   6500000    // c_norm2 [64]
#define WS_GRAM 6500064    // gram [64*64]
#define WS_P    6504160    // P = C^T W^T [64*10]
#define WS_X    6504800    // X = G^-1 P [64*10]
#define WS_U    6505440    // U = E C [8192*64] (reused by topk after k_ypred)
#define WS_MNB  7029728    // int[64] per-concept d2 min bits
#define WS_MXB  7029792    // int[64] per-concept d2 max bits
#define WS_GH   7029856    // u32[64*4096] per-concept global histogram
// end: 7292000 floats = 27.8 MiB
// ---- overlays inside U region (valid after k_ypred completes; stream-serial) ----
#define WS_CD2  6505440              // float[64*1024] candidate d2
#define WS_CS   (6505440+65536)      // float[64*1024] candidate s
#define WS_CIX  (6505440+131072)     // int[64*1024] candidate idx
#define WS_BST  (6505440+196608)     // int[64] bstar
#define WS_CNTB (6505440+196672)     // u32[64] count below bstar
#define WS_LOW  (6505440+196736)     // float[64] sum of s below bstar
#define WS_CCNT (6505440+196800)     // int[64] candidate counter

// ============ K_A: gram, c_norm2, P, init min/max ============
__global__ __launch_bounds__(256) void k_gram(
    const float* __restrict__ C, const float* __restrict__ W,
    float* __restrict__ gram, float* __restrict__ cn2, float* __restrict__ P,
    int* __restrict__ mnb, int* __restrict__ mxb)
{
  __shared__ float red[256];
  int c = blockIdx.x, t = threadIdx.x;
  int j = t & 63, part = t >> 6;
  float acc = 0.f;
  for (int d = part; d < DD; d += 4)
    acc = fmaf(C[d*NC_ + c], C[d*NC_ + j], acc);
  red[t] = acc;
  __syncthreads();
  if (part == 0) {
    float v = red[j] + red[j+64] + red[j+128] + red[j+192];
    gram[c*NC_ + j] = v;
    if (j == c) cn2[c] = v;
  }
  if (t == 0) { mnb[c] = 0x7f7fffff; mxb[c] = 0; }
  for (int jj = 0; jj < CC_; jj++) {
    float a = 0.f;
    for (int d = t; d < DD; d += 256)
      a = fmaf(C[d*NC_ + c], W[jj*DD + d], a);
    __syncthreads();
    red[t] = a;
    __syncthreads();
    for (int off = 128; off > 0; off >>= 1) {
      if (t < off) red[t] += red[t+off];
      __syncthreads();
    }
    if (t == 0) P[c*CC_ + jj] = red[0];
  }
}

// ============ K_B: Gauss-Jordan solve G X = P, gram scalars ============
__global__ __launch_bounds__(256) void k_solve(
    const float* __restrict__ gram, const float* __restrict__ P,
    float* __restrict__ X, float* __restrict__ outsc)
{
  __shared__ float A[NC_][76];   // [G | P], 74 used cols
  __shared__ float mcol[NC_];
  __shared__ float r1[256], r2[256], r3[256];
  int t = threadIdx.x;
  for (int i = t; i < NC_*NC_; i += 256) A[i >> 6][i & 63] = gram[i];
  for (int i = t; i < NC_*CC_; i += 256) A[i / CC_][64 + i % CC_] = P[i];
  float s_all = 0.f, s_diag = 0.f, s_dev = 0.f;
  for (int i = t; i < NC_*NC_; i += 256) {
    float g = gram[i];
    int rr = i >> 6, cc = i & 63;
    s_all += g;
    if (rr == cc) { s_diag += g; s_dev += fabsf(g - 1.f); }
    else s_dev += fabsf(g);
  }
  r1[t] = s_all; r2[t] = s_diag; r3[t] = s_dev;
  __syncthreads();
  for (int off = 128; off > 0; off >>= 1) {
    if (t < off) { r1[t] += r1[t+off]; r2[t] += r2[t+off]; r3[t] += r3[t+off]; }
    __syncthreads();
  }
  if (t == 0) {
    outsc[0] = 0.f;                            // L_sparse_1 accumulator (t4 adds)
    outsc[1] = (r1[0] - r2[0]) * (1.f/4096.f); // L_sparse_2
    outsc[2] = r2[0] * (1.f/4096.f);           // norm_metrics
    outsc[3] = r3[0] * (1.f/4096.f);           // similarity_penalty
  }
  for (int i = 0; i < NC_; i++) {
    __syncthreads();
    float piv = A[i][i];
    __syncthreads();
    if (t < 74) A[i][t] = A[i][t] / piv;
    __syncthreads();
    if (t < NC_) mcol[t] = A[t][i];
    __syncthreads();
    for (int e = t; e < NC_*74; e += 256) {
      int rr = e / 74, jj = e - rr*74;
      if (rr != i) A[rr][jj] = fmaf(-mcol[rr], A[i][jj], A[rr][jj]);
    }
  }
  __syncthreads();
  for (int i = t; i < NC_*CC_; i += 256) X[i] = A[i / CC_][64 + i % CC_];
}

// ============ K_C: fused U = E@C and orig_pred = E@W^T + b ============
__global__ __launch_bounds__(192) void k_EU(
    const float* __restrict__ E, const float* __restrict__ C,
    const float* __restrict__ W, const float* __restrict__ bias,
    float* __restrict__ U, float* __restrict__ orig)
{
  __shared__ __align__(16) float Et[32][36];  // [kk][row]
  __shared__ __align__(16) float Vt[32][96];  // [kk][col]
  int t = threadIdx.x;
  int r0 = blockIdx.x * 32;
  int rg = t & 15;       // rows rg*2, rg*2+1
  int cg = t >> 4;       // 0..11 -> cols cg*8..+7
  float acc[2][8] = {};
  for (int k0 = 0; k0 < DD; k0 += 32) {
    for (int lin = t; lin < 256; lin += 192) {        // 32 rows x 8 float4
      int row = lin >> 3, kq = (lin & 7) * 4;
      float4 v = *(const float4*)&E[(size_t)(r0+row)*DD + k0 + kq];
      Et[kq+0][row] = v.x; Et[kq+1][row] = v.y; Et[kq+2][row] = v.z; Et[kq+3][row] = v.w;
    }
    for (int lin = t; lin < 32*96; lin += 192) {
      int kk = lin / 96, cc = lin - kk*96;
      float v = 0.f;
      if (cc < 64)      v = C[(k0+kk)*NC_ + cc];
      else if (cc < 74) v = W[(cc-64)*DD + k0 + kk];
      Vt[kk][cc] = v;
    }
    __syncthreads();
    #pragma unroll 8
    for (int kk = 0; kk < 32; kk++) {
      float2 e2 = *(const float2*)&Et[kk][rg*2];
      float4 b0 = *(const float4*)&Vt[kk][cg*8];
      float4 b1 = *(const float4*)&Vt[kk][cg*8+4];
      float ev[2] = {e2.x, e2.y};
      float bv[8] = {b0.x,b0.y,b0.z,b0.w,b1.x,b1.y,b1.z,b1.w};
      #pragma unroll
      for (int r = 0; r < 2; r++)
        #pragma unroll
        for (int q = 0; q < 8; q++)
          acc[r][q] = fmaf(ev[r], bv[q], acc[r][q]);
    }
    __syncthreads();
  }
  #pragma unroll
  for (int r = 0; r < 2; r++) {
    int row = r0 + rg*2 + r;
    #pragma unroll
    for (int q = 0; q < 8; q++) {
      int col = cg*8 + q;
      if (col < NC_)      U[(size_t)row*NC_ + col] = acc[r][q];
      else if (col < 74)  orig[row*CC_ + (col-64)] = acc[r][q] + bias[col-64];
    }
  }
}

// ============ K_D: y_pred = U @ X + b ============
__global__ __launch_bounds__(256) void k_ypred(
    const float* __restrict__ U, const float* __restrict__ X,
    const float* __restrict__ bias, float* __restrict__ yp)
{
  __shared__ float Xs[NC_*CC_];
  __shared__ float bs[CC_];
  int t = threadIdx.x;
  for (int i = t; i < NC_*CC_; i += 256) Xs[i] = X[i];
  if (t < CC_) bs[t] = bias[t];
  __syncthreads();
  int r = blockIdx.x * 256 + t;
  float acc[CC_];
  #pragma unroll
  for (int j = 0; j < CC_; j++) acc[j] = bs[j];
  const float4* Ur = (const float4*)(U + (size_t)r * NC_);
  #pragma unroll 4
  for (int k4 = 0; k4 < 16; k4++) {
    float4 u = Ur[k4];
    float uv[4] = {u.x,u.y,u.z,u.w};
    #pragma unroll
    for (int kq = 0; kq < 4; kq++)
      #pragma unroll
      for (int j = 0; j < CC_; j++)
        acc[j] = fmaf(uv[kq], Xs[(k4*4+kq)*CC_ + j], acc[j]);
  }
  #pragma unroll
  for (int j = 0; j < CC_; j++) yp[(size_t)r*CC_ + j] = acc[j];
}

// ============ K_E: S = C^T T with register-prefetch double buffering ============
// Block: 64 concepts x 256 cols, 256 threads, 8x8 per thread.
// T14 async-STAGE split: issue chunk ch+1 global loads into regs before computing
// chunk ch from LDS; write regs->LDS after the barrier. Hides ~900cy HBM latency
// under the ~4096cy FMA phase (we run at ~1 wave/SIMD, so TLP can't do it).
__global__ __launch_bounds__(256) void k_bigS(
    const float* __restrict__ C, const float* __restrict__ T,
    float* __restrict__ S, float* __restrict__ tn2, const float* __restrict__ cn2,
    int* __restrict__ mnb, int* __restrict__ mxb)
{
  __shared__ __align__(16) float Ct[32][64];
  __shared__ __align__(16) float Tt[32][256];
  __shared__ int smn[64], smx[64];
  int t = threadIdx.x;
  int j0 = blockIdx.x * 256;
  int colg = t & 31, cgrp = t >> 5;
  int mycol = (t & 63) * 4;   // staging column group (constant per thread)
  int myrow = t >> 6;         // staging row phase 0..3
  int crow = t >> 4;          // C staging row 0..15
  int cc4 = (t & 15) * 4;     // C staging col group
  bool colok = (j0 + mycol) < NNN;
  const float4 f4z = {0.f,0.f,0.f,0.f};
  float acc[8][8] = {};
  float4 tn4 = {0.f,0.f,0.f,0.f};
  float4 rT[8], rC0, rC1;
  // prologue: chunk 0 -> regs
  #pragma unroll
  for (int p = 0; p < 8; p++) {
    int row = myrow + p*4;
    rT[p] = colok ? *(const float4*)&T[(size_t)row*NNN + j0 + mycol] : f4z;
  }
  rC0 = *(const float4*)&C[crow*NC_ + cc4];
  rC1 = *(const float4*)&C[(16+crow)*NC_ + cc4];
  for (int ch = 0; ch < 24; ch++) {
    __syncthreads();                 // previous chunk's readers done
    *(float4*)&Ct[crow][cc4]    = rC0;
    *(float4*)&Ct[16+crow][cc4] = rC1;
    #pragma unroll
    for (int p = 0; p < 8; p++) {
      float4 v = rT[p];
      *(float4*)&Tt[myrow + p*4][mycol] = v;
      tn4.x = fmaf(v.x,v.x,tn4.x); tn4.y = fmaf(v.y,v.y,tn4.y);
      tn4.z = fmaf(v.z,v.z,tn4.z); tn4.w = fmaf(v.w,v.w,tn4.w);
    }
    __syncthreads();                 // LDS writes visible
    if (ch < 23) {                   // issue NEXT chunk loads; wait lands at next write phase
      int k0n = (ch+1)*32;
      #pragma unroll
      for (int p = 0; p < 8; p++) {
        int row = k0n + myrow + p*4;
        rT[p] = colok ? *(const float4*)&T[(size_t)row*NNN + j0 + mycol] : f4z;
      }
      rC0 = *(const float4*)&C[(k0n+crow)*NC_ + cc4];
      rC1 = *(const float4*)&C[(k0n+16+crow)*NC_ + cc4];
    }
    #pragma unroll 8
    for (int kk = 0; kk < 32; kk++) {
      float4 a0 = *(const float4*)&Ct[kk][cgrp*4];
      float4 a1 = *(const float4*)&Ct[kk][32 + cgrp*4];
      float4 b0 = *(const float4*)&Tt[kk][colg*4];
      float4 b1 = *(const float4*)&Tt[kk][128 + colg*4];
      float av[8] = {a0.x,a0.y,a0.z,a0.w,a1.x,a1.y,a1.z,a1.w};
      float bv[8] = {b0.x,b0.y,b0.z,b0.w,b1.x,b1.y,b1.z,b1.w};
      #pragma unroll
      for (int i = 0; i < 8; i++)
        #pragma unroll
        for (int jq = 0; jq < 8; jq++)
          acc[i][jq] = fmaf(av[i], bv[jq], acc[i][jq]);
    }
  }
  __syncthreads();   // last compute done before Tt reuse
  // reduce t_norm2 partials (4 row-phases per column) via Tt rows 0..4
  *(float4*)&Tt[myrow][mycol] = tn4;
  __syncthreads();
  if (t < 64) {
    float4 s0 = *(const float4*)&Tt[0][t*4];
    float4 s1 = *(const float4*)&Tt[1][t*4];
    float4 s2 = *(const float4*)&Tt[2][t*4];
    float4 s3 = *(const float4*)&Tt[3][t*4];
    float4 ft;
    ft.x = (s0.x+s1.x)+(s2.x+s3.x); ft.y = (s0.y+s1.y)+(s2.y+s3.y);
    ft.z = (s0.z+s1.z)+(s2.z+s3.z); ft.w = (s0.w+s1.w)+(s2.w+s3.w);
    *(float4*)&Tt[4][t*4] = ft;
    if (j0 + t*4 < NNN) *(float4*)&tn2[j0 + t*4] = ft;
    smn[t] = 0x7f7fffff; smx[t] = 0;
  }
  __syncthreads();
  float4 tA = *(const float4*)&Tt[4][colg*4];
  float4 tB = *(const float4*)&Tt[4][128 + colg*4];
  float tnv[8] = {tA.x,tA.y,tA.z,tA.w,tB.x,tB.y,tB.z,tB.w};
  bool valA = (j0 + colg*4) < NNN;
  bool valB = (j0 + 128 + colg*4) < NNN;
  #pragma unroll
  for (int i = 0; i < 8; i++) {
    int c = (i < 4) ? (cgrp*4 + i) : (32 + cgrp*4 + (i-4));
    float cn = cn2[c];
    size_t base = (size_t)c * NNN + j0;
    if (valA) { float4 w = {acc[i][0],acc[i][1],acc[i][2],acc[i][3]}; *(float4*)&S[base + colg*4] = w; }
    if (valB) { float4 w = {acc[i][4],acc[i][5],acc[i][6],acc[i][7]}; *(float4*)&S[base + 128 + colg*4] = w; }
    float lmn = 1e30f, lmx = -1e30f;
    #pragma unroll
    for (int q = 0; q < 8; q++) {
      bool ok = (q < 4) ? valA : valB;
      if (ok) {
        float d2 = fmaf(-2.f, acc[i][q], cn + tnv[q]);
        lmn = fminf(lmn, d2); lmx = fmaxf(lmx, d2);
      }
    }
    if (lmn <= lmx) {
      atomicMin(&smn[c], __float_as_int(lmn));   // d2 > 0 -> int-bit compare valid
      atomicMax(&smx[c], __float_as_int(lmx));
    }
  }
  __syncthreads();
  if (t < 64) {
    atomicMin(&mnb[t], smn[t]);
    atomicMax(&mxb[t], smx[t]);
  }
}

// ============ top-k pipeline (4 kernels, 256-way parallel) ============
__device__ __forceinline__ int d2bin(float d2, float mn, float scale) {
  int b = (int)((d2 - mn) * scale);
  b = b < 0 ? 0 : b;
  return b > (NBIN-1) ? (NBIN-1) : b;
}

// t1: per-(concept,slice) LDS histogram -> merge into per-concept global hist
__global__ __launch_bounds__(1024) void t1_hist(
    const float* __restrict__ S, const float* __restrict__ tn2,
    const float* __restrict__ cn2, const int* __restrict__ mnb,
    const int* __restrict__ mxb, unsigned* __restrict__ gh)
{
  __shared__ unsigned hist[NBIN];
  int c = blockIdx.x >> 2, s = blockIdx.x & 3, t = threadIdx.x;
  float cn = cn2[c];
  float mn = __int_as_float(mnb[c]);
  float mx = __int_as_float(mxb[c]);
  float scale = (float)NBIN / fmaxf(mx - mn, 1e-12f);
  for (int i = t; i < NBIN; i += 1024) hist[i] = 0u;
  __syncthreads();
  const float4* Sr = (const float4*)(S + (size_t)c * NNN) + s * SLICE_N4;
  const float4* Tn = (const float4*)tn2 + s * SLICE_N4;
  for (int i = t; i < SLICE_N4; i += 1024) {
    float4 s4 = Sr[i];
    float4 t4 = Tn[i];
    atomicAdd(&hist[d2bin(fmaf(-2.f, s4.x, cn + t4.x), mn, scale)], 1u);
    atomicAdd(&hist[d2bin(fmaf(-2.f, s4.y, cn + t4.y), mn, scale)], 1u);
    atomicAdd(&hist[d2bin(fmaf(-2.f, s4.z, cn + t4.z), mn, scale)], 1u);
    atomicAdd(&hist[d2bin(fmaf(-2.f, s4.w, cn + t4.w), mn, scale)], 1u);
  }
  __syncthreads();
  for (int i = t; i < NBIN; i += 1024) {
    unsigned v = hist[i];
    if (v) atomicAdd(&gh[c*NBIN + i], v);
  }
}

// t2: per-concept cumsum -> bstar, cntb; init accumulators
__global__ __launch_bounds__(1024) void t2_scan(
    const unsigned* __restrict__ gh, int* __restrict__ bst,
    unsigned* __restrict__ cntb, float* __restrict__ low, int* __restrict__ ccnt)
{
  __shared__ unsigned hist[NBIN];
  __shared__ unsigned tth[1024];
  __shared__ unsigned gth[32];
  __shared__ int bs_;
  __shared__ unsigned cb_;
  int c = blockIdx.x, t = threadIdx.x;
  for (int i = t; i < NBIN; i += 1024) hist[i] = gh[c*NBIN + i];
  __syncthreads();
  int base = t * 4;
  unsigned h0 = hist[base], h1 = hist[base+1], h2 = hist[base+2], h3 = hist[base+3];
  unsigned i0 = h0, i1 = i0 + h1, i2 = i1 + h2, i3 = i2 + h3;
  tth[t] = i3;
  __syncthreads();
  if (t < 32) { unsigned s = 0; for (int q = 0; q < 32; q++) s += tth[t*32+q]; gth[t] = s; }
  __syncthreads();
  if (t == 0) { unsigned s = 0; for (int q = 0; q < 32; q++) { unsigned x = gth[q]; gth[q] = s; s += x; } }
  __syncthreads();
  if (t < 32) { unsigned s = gth[t]; for (int q = 0; q < 32; q++) { unsigned x = tth[t*32+q]; tth[t*32+q] = s; s += x; } }
  __syncthreads();
  unsigned off = tth[t];
  hist[base]   = off + i0;
  hist[base+1] = off + i1;
  hist[base+2] = off + i2;
  hist[base+3] = off + i3;
  __syncthreads();
  #pragma unroll
  for (int q = 0; q < 4; q++) {
    int bb = base + q;
    unsigned cum = hist[bb];
    unsigned prev = (bb == 0) ? 0u : hist[bb-1];
    if (cum >= (unsigned)KTOP && prev < (unsigned)KTOP) { bs_ = bb; cb_ = prev; }
  }
  __syncthreads();
  if (t == 0) { bst[c] = bs_; cntb[c] = cb_; low[c] = 0.f; ccnt[c] = 0; }
}

// t3: per-(concept,slice): sum s below bstar; collect bstar-bin candidates
__global__ __launch_bounds__(1024) void t3_collect(
    const float* __restrict__ S, const float* __restrict__ tn2,
    const float* __restrict__ cn2, const int* __restrict__ mnb,
    const int* __restrict__ mxb, const int* __restrict__ bst,
    float* __restrict__ cd2, float* __restrict__ cs, int* __restrict__ cix,
    int* __restrict__ ccnt, float* __restrict__ low)
{
  __shared__ float redf[1024];
  int c = blockIdx.x >> 2, s = blockIdx.x & 3, t = threadIdx.x;
  float cn = cn2[c];
  float mn = __int_as_float(mnb[c]);
  float mx = __int_as_float(mxb[c]);
  float scale = (float)NBIN / fmaxf(mx - mn, 1e-12f);
  int bstar = bst[c];
  const float4* Sr = (const float4*)(S + (size_t)c * NNN) + s * SLICE_N4;
  const float4* Tn = (const float4*)tn2 + s * SLICE_N4;
  float ssum = 0.f;
  for (int i = t; i < SLICE_N4; i += 1024) {
    float4 s4 = Sr[i];
    float4 t4 = Tn[i];
    float sv[4] = {s4.x, s4.y, s4.z, s4.w};
    float tv[4] = {t4.x, t4.y, t4.z, t4.w};
    #pragma unroll
    for (int q = 0; q < 4; q++) {
      float dd = fmaf(-2.f, sv[q], cn + tv[q]);
      int b = d2bin(dd, mn, scale);
      if (b < bstar) ssum += sv[q];
      else if (b == bstar) {
        int id = atomicAdd(&ccnt[c], 1);
        if (id < CCAP) {
          cd2[c*CCAP + id] = dd;
          cs [c*CCAP + id] = sv[q];
          cix[c*CCAP + id] = s*NN4_ + i*4 + q;   // true element index
        }
      }
    }
  }
  redf[t] = ssum;
  __syncthreads();
  for (int offr = 512; offr > 0; offr >>= 1) {
    if (t < offr) redf[t] += redf[t + offr];
    __syncthreads();
  }
  if (t == 0) atomicAdd(&low[c], redf[0]);
}

// t4: per-concept stable (d2,idx) tie-break among candidates; accumulate L
__global__ __launch_bounds__(256) void t4_final(
    const float* __restrict__ cd2, const float* __restrict__ cs,
    const int* __restrict__ cix, const int* __restrict__ ccnt,
    const unsigned* __restrict__ cntb, const float* __restrict__ low,
    float* __restrict__ Lout)
{
  __shared__ float d2s[CCAP], ss[CCAP];
  __shared__ int ix[CCAP];
  int c = blockIdx.x, t = threadIdx.x;
  int nc = ccnt[c]; nc = nc < CCAP ? nc : CCAP;
  for (int i = t; i < nc; i += 256) {
    d2s[i] = cd2[c*CCAP + i];
    ss[i]  = cs [c*CCAP + i];
    ix[i]  = cix[c*CCAP + i];
  }
  __syncthreads();
  if (t == 0) {
    int need = KTOP - (int)cntb[c];
    float extra = 0.f;
    for (int sel = 0; sel < need; sel++) {
      float bd = 3.4e38f; int bi = -1; int bx = 0x7fffffff;
      for (int q = 0; q < nc; q++) {
        if (ix[q] >= 0) {
          float dq = d2s[q];
          if (dq < bd || (dq == bd && ix[q] < bx)) { bd = dq; bi = q; bx = ix[q]; }
        }
      }
      if (bi < 0) break;
      extra += ss[bi];
      ix[bi] = -1;
    }
    atomicAdd(Lout, (low[c] + extra) * (1.f / (float)(KTOP * NC_)));
  }
}

// ============ host-side launch ============
extern "C" void kernel_launch(void* const* d_in, const int* in_sizes, int n_in,
                              void* d_out, int out_size, void* d_ws, size_t ws_size,
                              hipStream_t stream) {
  const float* E    = (const float*)d_in[0];  // train_embedding [8192,768]
  const float* Cm   = (const float*)d_in[2];  // concept [768,64]
  const float* Tm   = (const float*)d_in[3];  // train_embeddings_T [768,100000]
  const float* W    = (const float*)d_in[4];  // [10,768]
  const float* bias = (const float*)d_in[5];  // [10]
  float* out = (float*)d_out;
  float* ws  = (float*)d_ws;

  float* S    = ws + WS_S;
  float* tn2  = ws + WS_TN;
  float* cn2  = ws + WS_CN;
  float* gram = ws + WS_GRAM;
  float* P    = ws + WS_P;
  float* X    = ws + WS_X;
  float* U    = ws + WS_U;
  int*   mnb  = (int*)(ws + WS_MNB);
  int*   mxb  = (int*)(ws + WS_MXB);
  unsigned* gh = (unsigned*)(ws + WS_GH);
  float* cd2  = ws + WS_CD2;
  float* cs   = ws + WS_CS;
  int*   cix  = (int*)(ws + WS_CIX);
  int*   bst  = (int*)(ws + WS_BST);
  unsigned* cntb = (unsigned*)(ws + WS_CNTB);
  float* low  = ws + WS_LOW;
  int*   ccnt = (int*)(ws + WS_CCNT);

  float* orig = out;            // [0 .. 81919]
  float* yp   = out + 81920;    // [81920 .. 163839]
  float* sc   = out + 163840;   // L_sparse_1, L_sparse_2, norm_metrics, similarity_penalty

  hipLaunchKernelGGL(k_gram,  dim3(64),  dim3(256),  0, stream, Cm, W, gram, cn2, P, mnb, mxb);
  hipLaunchKernelGGL(k_solve, dim3(1),   dim3(256),  0, stream, gram, P, X, sc);
  hipLaunchKernelGGL(k_EU,    dim3(256), dim3(192),  0, stream, E, Cm, W, bias, U, orig);
  hipLaunchKernelGGL(k_ypred, dim3(32),  dim3(256),  0, stream, U, X, bias, yp);
  hipLaunchKernelGGL(k_bigS,  dim3(391), dim3(256),  0, stream, Cm, Tm, S, tn2, cn2, mnb, mxb);
  hipMemsetAsync(gh, 0, (size_t)NC_ * NBIN * sizeof(unsigned), stream);
  hipLaunchKernelGGL(t1_hist,    dim3(256), dim3(1024), 0, stream, S, tn2, cn2, mnb, mxb, gh);
  hipLaunchKernelGGL(t2_scan,    dim3(64),  dim3(1024), 0, stream, gh, bst, cntb, low, ccnt);
  hipLaunchKernelGGL(t3_collect, dim3(256), dim3(1024), 0, stream, S, tn2, cn2, mnb, mxb, bst, cd2, cs, cix, ccnt, low);
  hipLaunchKernelGGL(t4_final,   dim3(64),  dim3(256),  0, stream, cd2, cs, cix, ccnt, cntb, low, sc);
}